// Round 1
// baseline (340.422 us; speedup 1.0000x reference)
//
#include <hip/hip_runtime.h>
#include <hip/hip_bf16.h>

#define NN 4096
#define CAP 128   // max nnz per row tracked (binomial mean 41, sd 6.4; 128 = 13.6 sigma)

__device__ __forceinline__ float lrelu(float v) { return v >= 0.f ? v : 0.2f * v; }

// ---------------------------------------------------------------------------
// K1: xwA1=x@W1[0], xwB1=x@W1[1], xwA2=x@W2[0], xwB2=x@W2[1], v0=x@W0,
//     a/b attention vectors (a[i]=sum_o xwA[i,o]att[o]+xwB[i,o]att[32+o], etc),
//     Bt = (x@W0)^T as bf16 for the P-GEMM.
// block=256: 8 rows x 32 outs. W matrices staged in LDS (20 KB).
// ---------------------------------------------------------------------------
__global__ __launch_bounds__(256) void k_prep(
    const float* __restrict__ x,
    const float* __restrict__ W1, const float* __restrict__ W2,
    const float* __restrict__ W0,
    const float* __restrict__ att1, const float* __restrict__ att2,
    float* __restrict__ xwA1, float* __restrict__ xwB1,
    float* __restrict__ xwA2, float* __restrict__ xwB2,
    float* __restrict__ a1, float* __restrict__ b1,
    float* __restrict__ a2, float* __restrict__ b2,
    __hip_bfloat16* __restrict__ Bt)
{
    __shared__ float wl[5120];   // W1(2048) W2(2048) W0(1024)
    __shared__ float xs[256];    // 8 rows x 32
    const int t = threadIdx.x;
    for (int i = t; i < 2048; i += 256) { wl[i] = W1[i]; wl[2048 + i] = W2[i]; }
    for (int i = t; i < 1024; i += 256) wl[4096 + i] = W0[i];
    const int rowBase = blockIdx.x * 8;
    xs[t] = x[rowBase * 32 + t];
    __syncthreads();

    const int o = t & 31, r = t >> 5;
    const int row = rowBase + r;
    const float* xr = &xs[r * 32];
    float vA1 = 0.f, vB1 = 0.f, vA2 = 0.f, vB2 = 0.f, v0 = 0.f;
#pragma unroll
    for (int f = 0; f < 32; ++f) {
        const float xv = xr[f];
        vA1 += xv * wl[f * 32 + o];
        vB1 += xv * wl[1024 + f * 32 + o];
        vA2 += xv * wl[2048 + f * 32 + o];
        vB2 += xv * wl[3072 + f * 32 + o];
        v0  += xv * wl[4096 + f * 32 + o];
    }
    xwA1[row * 32 + o] = vA1;
    xwB1[row * 32 + o] = vB1;
    xwA2[row * 32 + o] = vA2;
    xwB2[row * 32 + o] = vB2;
    Bt[(size_t)o * NN + row] = __float2bfloat16(v0);

    // attention scalars: reduce over o within each 32-lane half-wave
    float pa1 = vA1 * att1[o]      + vB1 * att1[32 + o];
    float pb1 = vA1 * att1[64 + o] + vB1 * att1[96 + o];
    float pa2 = vA2 * att2[o]      + vB2 * att2[32 + o];
    float pb2 = vA2 * att2[64 + o] + vB2 * att2[96 + o];
#pragma unroll
    for (int m = 1; m <= 16; m <<= 1) {
        pa1 += __shfl_xor(pa1, m); pb1 += __shfl_xor(pb1, m);
        pa2 += __shfl_xor(pa2, m); pb2 += __shfl_xor(pb2, m);
    }
    if (o == 0) { a1[row] = pa1; b1[row] = pb1; a2[row] = pa2; b2[row] = pb2; }
}

// ---------------------------------------------------------------------------
// K2: per (row, branch): scan dense L row (16 KB coalesced float4), build CSR
// column list via LDS atomic slot counter, and fused y[row] = L[row,:] @ xwB.
// HBM-bound: 128 MB total.
// ---------------------------------------------------------------------------
__global__ __launch_bounds__(256) void k_scan(
    const float* __restrict__ Ld, const float* __restrict__ Lu,
    const float* __restrict__ xwB1, const float* __restrict__ xwB2,
    int* __restrict__ csr, int* __restrict__ cntArr,
    float* __restrict__ y1, float* __restrict__ y2)
{
    const int row = blockIdx.x;
    const int br  = blockIdx.y;
    const float* L   = br ? Lu : Ld;
    const float* xwB = br ? xwB2 : xwB1;
    int*   csrB = csr + (size_t)br * NN * CAP;
    int*   cntB = cntArr + br * NN;
    float* y    = br ? y2 : y1;

    __shared__ int   sidx[CAP];
    __shared__ float sval[CAP];
    __shared__ int   scnt;
    __shared__ float red[256];
    const int t = threadIdx.x;
    if (t == 0) scnt = 0;
    __syncthreads();

    const float4* L4 = (const float4*)(L + (size_t)row * NN);
#pragma unroll
    for (int it = 0; it < 4; ++it) {
        const int i4 = it * 256 + t;
        const float4 v = L4[i4];
        const int c0 = i4 * 4;
        if (v.x != 0.f) { int s = atomicAdd(&scnt, 1); if (s < CAP) { sidx[s] = c0;     sval[s] = v.x; } }
        if (v.y != 0.f) { int s = atomicAdd(&scnt, 1); if (s < CAP) { sidx[s] = c0 + 1; sval[s] = v.y; } }
        if (v.z != 0.f) { int s = atomicAdd(&scnt, 1); if (s < CAP) { sidx[s] = c0 + 2; sval[s] = v.z; } }
        if (v.w != 0.f) { int s = atomicAdd(&scnt, 1); if (s < CAP) { sidx[s] = c0 + 3; sval[s] = v.w; } }
    }
    __syncthreads();
    const int cnt = min(scnt, CAP);
    for (int s = t; s < cnt; s += 256) csrB[(size_t)row * CAP + s] = sidx[s];
    if (t == 0) cntB[row] = cnt;

    // y[row,:] = sum_s sval[s] * xwB[sidx[s], :]; 8 slot-groups x 32 features
    const int o = t & 31, g = t >> 5;
    float acc = 0.f;
    for (int s = g; s < cnt; s += 8) acc += sval[s] * xwB[(size_t)sidx[s] * 32 + o];
    red[t] = acc;
    __syncthreads();
    if (t < 32) {
        float tot = 0.f;
#pragma unroll
        for (int g2 = 0; g2 < 8; ++g2) tot += red[g2 * 32 + t];
        y[(size_t)row * 32 + t] = tot;
    }
}

// ---------------------------------------------------------------------------
// K3: per (row, branch) online softmax over CSR entries + weighted gather:
// z[i] = (1/s) sum_j exp(lrelu(a_i+b_j) - m) * (xwA[j,:] + y[j,:])
// One wave per row, 4 rows per block. xwA / y gathers are L2-resident (512 KB).
// ---------------------------------------------------------------------------
__global__ __launch_bounds__(256) void k_attn(
    const int* __restrict__ csr, const int* __restrict__ cntArr,
    const float* __restrict__ a1, const float* __restrict__ b1,
    const float* __restrict__ a2, const float* __restrict__ b2,
    const float* __restrict__ xwA1, const float* __restrict__ xwA2,
    const float* __restrict__ y1, const float* __restrict__ y2,
    float* __restrict__ z1, float* __restrict__ z2)
{
    const int br = blockIdx.y;
    const int* csrB = csr + (size_t)br * NN * CAP;
    const int* cntB = cntArr + br * NN;
    const float* aA  = br ? a2 : a1;
    const float* bA  = br ? b2 : b1;
    const float* xwA = br ? xwA2 : xwA1;
    const float* y   = br ? y2 : y1;
    float* z = br ? z2 : z1;

    __shared__ float elds[4 * CAP];
    const int w = threadIdx.x >> 6, lane = threadIdx.x & 63;
    const int row = blockIdx.x * 4 + w;
    const int cnt = cntB[row];
    const float ai = aA[row];
    const int* ci = csrB + (size_t)row * CAP;
    float* ew = elds + w * CAP;

    float lmax = -1e30f;
    for (int s = lane; s < cnt; s += 64) {
        const float e = lrelu(ai + bA[ci[s]]);
        ew[s] = e;
        lmax = fmaxf(lmax, e);
    }
#pragma unroll
    for (int m = 1; m <= 32; m <<= 1) lmax = fmaxf(lmax, __shfl_xor(lmax, m));
    float ssum = 0.f;
    for (int s = lane; s < cnt; s += 64) ssum += __expf(ew[s] - lmax);
#pragma unroll
    for (int m = 1; m <= 32; m <<= 1) ssum += __shfl_xor(ssum, m);

    const int h = lane >> 5, o = lane & 31;
    float acc = 0.f;
    for (int s = h; s < cnt; s += 2) {
        const float wgt = __expf(ew[s] - lmax);
        const int col = ci[s];
        acc += wgt * (xwA[(size_t)col * 32 + o] + y[(size_t)col * 32 + o]);
    }
    acc += __shfl_xor(acc, 32);
    if (lane < 32) z[(size_t)row * 32 + o] = (cnt > 0) ? acc / ssum : 0.f;
}

// ---------------------------------------------------------------------------
// K4: partial = P[:, krange] @ B[krange, :]  (B = x@W0, stored transposed bf16)
// Wave handles 4 rows, lanes along k (float4 coalesced P stream). Bt reused
// 4x from L2 (256 MB L2 traffic). K-split 2 for occupancy. Butterfly reduce
// over 64 lanes -> LDS -> coalesced store.
// ---------------------------------------------------------------------------
__global__ __launch_bounds__(256) void k_pgemm(
    const float* __restrict__ P, const __hip_bfloat16* __restrict__ Bt,
    float* __restrict__ partial)
{
    const int w = threadIdx.x >> 6, lane = threadIdx.x & 63;
    const int row0 = blockIdx.x * 16 + w * 4;
    const int ks = blockIdx.y;            // k-split 0/1, each 2048 k
    const float4*  P4  = (const float4*)P;        // 1024 float4 per row
    const ushort4* Bt4 = (const ushort4*)Bt;      // 1024 ushort4 per Bt row

    float acc[4][32];
#pragma unroll
    for (int r = 0; r < 4; ++r)
#pragma unroll
        for (int o = 0; o < 32; ++o) acc[r][o] = 0.f;

    for (int it = 0; it < 8; ++it) {
        const int kq = ks * 512 + it * 64 + lane;
        const float4 p0 = P4[(size_t)(row0 + 0) * 1024 + kq];
        const float4 p1 = P4[(size_t)(row0 + 1) * 1024 + kq];
        const float4 p2 = P4[(size_t)(row0 + 2) * 1024 + kq];
        const float4 p3 = P4[(size_t)(row0 + 3) * 1024 + kq];
#pragma unroll
        for (int o = 0; o < 32; ++o) {
            const ushort4 bu = Bt4[(size_t)o * 1024 + kq];
            const float bx = __uint_as_float((unsigned)bu.x << 16);
            const float by = __uint_as_float((unsigned)bu.y << 16);
            const float bz = __uint_as_float((unsigned)bu.z << 16);
            const float bw = __uint_as_float((unsigned)bu.w << 16);
            acc[0][o] += p0.x * bx + p0.y * by + p0.z * bz + p0.w * bw;
            acc[1][o] += p1.x * bx + p1.y * by + p1.z * bz + p1.w * bw;
            acc[2][o] += p2.x * bx + p2.y * by + p2.z * bz + p2.w * bw;
            acc[3][o] += p3.x * bx + p3.y * by + p3.z * bz + p3.w * bw;
        }
    }
    // reduce over 64 lanes (k-partials)
#pragma unroll
    for (int m = 1; m <= 32; m <<= 1)
#pragma unroll
        for (int r = 0; r < 4; ++r)
#pragma unroll
            for (int o = 0; o < 32; ++o)
                acc[r][o] += __shfl_xor(acc[r][o], m);

    __shared__ float swl[4 * 128];
    if (lane == 0) {
#pragma unroll
        for (int r = 0; r < 4; ++r)
#pragma unroll
            for (int o = 0; o < 32; ++o) swl[w * 128 + r * 32 + o] = acc[r][o];
    }
    __syncthreads();
    if (lane < 32) {
#pragma unroll
        for (int r = 0; r < 4; ++r)
            partial[((size_t)ks * NN + row0 + r) * 32 + lane] = swl[w * 128 + r * 32 + lane];
    }
}

// ---------------------------------------------------------------------------
// K5: out = z1 + z2 + partial0 + partial1
// ---------------------------------------------------------------------------
__global__ __launch_bounds__(256) void k_combine(
    const float4* __restrict__ z1, const float4* __restrict__ z2,
    const float4* __restrict__ p0, const float4* __restrict__ p1,
    float4* __restrict__ out)
{
    const int i = blockIdx.x * 256 + threadIdx.x;
    const float4 a = z1[i], b = z2[i], c = p0[i], d = p1[i];
    float4 r;
    r.x = a.x + b.x + c.x + d.x;
    r.y = a.y + b.y + c.y + d.y;
    r.z = a.z + b.z + c.z + d.z;
    r.w = a.w + b.w + c.w + d.w;
    out[i] = r;
}

extern "C" void kernel_launch(void* const* d_in, const int* in_sizes, int n_in,
                              void* d_out, int out_size, void* d_ws, size_t ws_size,
                              hipStream_t stream) {
    (void)in_sizes; (void)n_in; (void)out_size; (void)ws_size;
    const float* x    = (const float*)d_in[0];
    const float* Ld   = (const float*)d_in[1];
    const float* Lu   = (const float*)d_in[2];
    const float* P    = (const float*)d_in[3];
    const float* W1   = (const float*)d_in[4];
    const float* W2   = (const float*)d_in[5];
    const float* W0   = (const float*)d_in[6];
    const float* att1 = (const float*)d_in[7];
    const float* att2 = (const float*)d_in[8];

    float* ws = (float*)d_ws;
    float* xwA1 = ws;                 // 131072 each
    float* xwB1 = ws + 131072;
    float* xwA2 = ws + 262144;
    float* xwB2 = ws + 393216;
    float* y1   = ws + 524288;
    float* y2   = ws + 655360;
    float* z1   = ws + 786432;
    float* z2   = ws + 917504;
    float* a1   = ws + 1048576;       // 4096 each
    float* b1   = ws + 1052672;
    float* a2   = ws + 1056768;
    float* b2   = ws + 1060864;
    float* partial = ws + 1064960;    // 2 * 131072
    __hip_bfloat16* Bt = (__hip_bfloat16*)(ws + 1327104);  // 131072 bf16
    int* csr = (int*)(ws + 1392640);  // 2 * 4096 * 128 ints
    int* cnt = (int*)(ws + 2441216);  // 2 * 4096 ints
    // total ~9.8 MB of workspace

    k_prep<<<512, 256, 0, stream>>>(x, W1, W2, W0, att1, att2,
                                    xwA1, xwB1, xwA2, xwB2, a1, b1, a2, b2, Bt);
    k_scan<<<dim3(NN, 2), 256, 0, stream>>>(Ld, Lu, xwB1, xwB2, csr, cnt, y1, y2);
    k_attn<<<dim3(NN / 4, 2), 256, 0, stream>>>(csr, cnt, a1, b1, a2, b2,
                                                xwA1, xwA2, y1, y2, z1, z2);
    k_pgemm<<<dim3(256, 2), 256, 0, stream>>>(P, Bt, partial);
    k_combine<<<128, 256, 0, stream>>>((const float4*)z1, (const float4*)z2,
                                       (const float4*)partial,
                                       (const float4*)(partial + 131072),
                                       (float4*)d_out);
}

// Round 2
// 242.098 us; speedup vs baseline: 1.4061x; 1.4061x over previous
//
#include <hip/hip_runtime.h>
#include <hip/hip_bf16.h>

#define NN 4096
#define CAP 128   // max nnz per row tracked (binomial mean 41, sd 6.4)
#define KS 8      // k-splits for P-GEMM

typedef __attribute__((ext_vector_type(8))) short bf16x8;
typedef __attribute__((ext_vector_type(4))) float f32x4;

__device__ __forceinline__ float lrelu(float v) { return v >= 0.f ? v : 0.2f * v; }

// fp32 -> bf16 bits, round-to-nearest-even (inputs are finite)
__device__ __forceinline__ ushort f2bu(float f) {
    unsigned u = __float_as_uint(f);
    return (ushort)((u + 0x7FFFu + ((u >> 16) & 1u)) >> 16);
}

// ---------------------------------------------------------------------------
// K1: xwA1=x@W1[0], xwB1=x@W1[1], xwA2=x@W2[0], xwB2=x@W2[1], v0=x@W0,
//     a/b attention vectors, Bt = (x@W0)^T as bf16 for the P-GEMM.
// ---------------------------------------------------------------------------
__global__ __launch_bounds__(256) void k_prep(
    const float* __restrict__ x,
    const float* __restrict__ W1, const float* __restrict__ W2,
    const float* __restrict__ W0,
    const float* __restrict__ att1, const float* __restrict__ att2,
    float* __restrict__ xwA1, float* __restrict__ xwB1,
    float* __restrict__ xwA2, float* __restrict__ xwB2,
    float* __restrict__ a1, float* __restrict__ b1,
    float* __restrict__ a2, float* __restrict__ b2,
    __hip_bfloat16* __restrict__ Bt)
{
    __shared__ float wl[5120];   // W1(2048) W2(2048) W0(1024)
    __shared__ float xs[256];    // 8 rows x 32
    const int t = threadIdx.x;
    for (int i = t; i < 2048; i += 256) { wl[i] = W1[i]; wl[2048 + i] = W2[i]; }
    for (int i = t; i < 1024; i += 256) wl[4096 + i] = W0[i];
    const int rowBase = blockIdx.x * 8;
    xs[t] = x[rowBase * 32 + t];
    __syncthreads();

    const int o = t & 31, r = t >> 5;
    const int row = rowBase + r;
    const float* xr = &xs[r * 32];
    float vA1 = 0.f, vB1 = 0.f, vA2 = 0.f, vB2 = 0.f, v0 = 0.f;
#pragma unroll
    for (int f = 0; f < 32; ++f) {
        const float xv = xr[f];
        vA1 += xv * wl[f * 32 + o];
        vB1 += xv * wl[1024 + f * 32 + o];
        vA2 += xv * wl[2048 + f * 32 + o];
        vB2 += xv * wl[3072 + f * 32 + o];
        v0  += xv * wl[4096 + f * 32 + o];
    }
    xwA1[row * 32 + o] = vA1;
    xwB1[row * 32 + o] = vB1;
    xwA2[row * 32 + o] = vA2;
    xwB2[row * 32 + o] = vB2;
    ((ushort*)Bt)[(size_t)o * NN + row] = f2bu(v0);

    float pa1 = vA1 * att1[o]      + vB1 * att1[32 + o];
    float pb1 = vA1 * att1[64 + o] + vB1 * att1[96 + o];
    float pa2 = vA2 * att2[o]      + vB2 * att2[32 + o];
    float pb2 = vA2 * att2[64 + o] + vB2 * att2[96 + o];
#pragma unroll
    for (int m = 1; m <= 16; m <<= 1) {
        pa1 += __shfl_xor(pa1, m); pb1 += __shfl_xor(pb1, m);
        pa2 += __shfl_xor(pa2, m); pb2 += __shfl_xor(pb2, m);
    }
    if (o == 0) { a1[row] = pa1; b1[row] = pb1; a2[row] = pa2; b2[row] = pb2; }
}

// ---------------------------------------------------------------------------
// K2: per (row, branch): scan dense L row, build CSR column list, fused
// y[row] = L[row,:] @ xwB.  HBM-bound: 128 MB total.
// ---------------------------------------------------------------------------
__global__ __launch_bounds__(256) void k_scan(
    const float* __restrict__ Ld, const float* __restrict__ Lu,
    const float* __restrict__ xwB1, const float* __restrict__ xwB2,
    int* __restrict__ csr, int* __restrict__ cntArr,
    float* __restrict__ y1, float* __restrict__ y2)
{
    const int row = blockIdx.x;
    const int br  = blockIdx.y;
    const float* L   = br ? Lu : Ld;
    const float* xwB = br ? xwB2 : xwB1;
    int*   csrB = csr + (size_t)br * NN * CAP;
    int*   cntB = cntArr + br * NN;
    float* y    = br ? y2 : y1;

    __shared__ int   sidx[CAP];
    __shared__ float sval[CAP];
    __shared__ int   scnt;
    __shared__ float red[256];
    const int t = threadIdx.x;
    if (t == 0) scnt = 0;
    __syncthreads();

    const float4* L4 = (const float4*)(L + (size_t)row * NN);
#pragma unroll
    for (int it = 0; it < 4; ++it) {
        const int i4 = it * 256 + t;
        const float4 v = L4[i4];
        const int c0 = i4 * 4;
        if (v.x != 0.f) { int s = atomicAdd(&scnt, 1); if (s < CAP) { sidx[s] = c0;     sval[s] = v.x; } }
        if (v.y != 0.f) { int s = atomicAdd(&scnt, 1); if (s < CAP) { sidx[s] = c0 + 1; sval[s] = v.y; } }
        if (v.z != 0.f) { int s = atomicAdd(&scnt, 1); if (s < CAP) { sidx[s] = c0 + 2; sval[s] = v.z; } }
        if (v.w != 0.f) { int s = atomicAdd(&scnt, 1); if (s < CAP) { sidx[s] = c0 + 3; sval[s] = v.w; } }
    }
    __syncthreads();
    const int cnt = min(scnt, CAP);
    for (int s = t; s < cnt; s += 256) csrB[(size_t)row * CAP + s] = sidx[s];
    if (t == 0) cntB[row] = cnt;

    const int o = t & 31, g = t >> 5;
    float acc = 0.f;
    for (int s = g; s < cnt; s += 8) acc += sval[s] * xwB[(size_t)sidx[s] * 32 + o];
    red[t] = acc;
    __syncthreads();
    if (t < 32) {
        float tot = 0.f;
#pragma unroll
        for (int g2 = 0; g2 < 8; ++g2) tot += red[g2 * 32 + t];
        y[(size_t)row * 32 + t] = tot;
    }
}

// ---------------------------------------------------------------------------
// K3: per (row, branch) online softmax over CSR entries + weighted gather.
// ---------------------------------------------------------------------------
__global__ __launch_bounds__(256) void k_attn(
    const int* __restrict__ csr, const int* __restrict__ cntArr,
    const float* __restrict__ a1, const float* __restrict__ b1,
    const float* __restrict__ a2, const float* __restrict__ b2,
    const float* __restrict__ xwA1, const float* __restrict__ xwA2,
    const float* __restrict__ y1, const float* __restrict__ y2,
    float* __restrict__ z1, float* __restrict__ z2)
{
    const int br = blockIdx.y;
    const int* csrB = csr + (size_t)br * NN * CAP;
    const int* cntB = cntArr + br * NN;
    const float* aA  = br ? a2 : a1;
    const float* bA  = br ? b2 : b1;
    const float* xwA = br ? xwA2 : xwA1;
    const float* y   = br ? y2 : y1;
    float* z = br ? z2 : z1;

    __shared__ float elds[4 * CAP];
    const int w = threadIdx.x >> 6, lane = threadIdx.x & 63;
    const int row = blockIdx.x * 4 + w;
    const int cnt = cntB[row];
    const float ai = aA[row];
    const int* ci = csrB + (size_t)row * CAP;
    float* ew = elds + w * CAP;

    float lmax = -1e30f;
    for (int s = lane; s < cnt; s += 64) {
        const float e = lrelu(ai + bA[ci[s]]);
        ew[s] = e;
        lmax = fmaxf(lmax, e);
    }
#pragma unroll
    for (int m = 1; m <= 32; m <<= 1) lmax = fmaxf(lmax, __shfl_xor(lmax, m));
    float ssum = 0.f;
    for (int s = lane; s < cnt; s += 64) ssum += __expf(ew[s] - lmax);
#pragma unroll
    for (int m = 1; m <= 32; m <<= 1) ssum += __shfl_xor(ssum, m);

    const int h = lane >> 5, o = lane & 31;
    float acc = 0.f;
    for (int s = h; s < cnt; s += 2) {
        const float wgt = __expf(ew[s] - lmax);
        const int col = ci[s];
        acc += wgt * (xwA[(size_t)col * 32 + o] + y[(size_t)col * 32 + o]);
    }
    acc += __shfl_xor(acc, 32);
    if (lane < 32) z[(size_t)row * 32 + o] = (cnt > 0) ? acc / ssum : 0.f;
}

// ---------------------------------------------------------------------------
// K4 (MFMA rewrite): partial[ks] = P[:, krange] @ B[krange, :]
// Block = 64 rows x 32 cols x 512 k; 4 chunks of 128 k, double-buffered LDS.
// P fp32 -> bf16 on the fly. Fragments stored pre-swizzled in lane order so
// compute reads are ds_read_b128 with lane i -> consecutive 16B (conflict-free).
// ---------------------------------------------------------------------------
__global__ __launch_bounds__(256) void k_pgemm(
    const float* __restrict__ P, const ushort* __restrict__ Bt,
    float* __restrict__ partial)
{
    // sA: per buf, 16 (w,kk) groups x 64 lanes x 8 ushorts = 16 KB
    // sB: per buf,  8 (kk,nt) groups x 64 lanes x 8 ushorts =  8 KB
    __shared__ ushort sA[2][16 * 64 * 8];
    __shared__ ushort sB[2][8 * 64 * 8];
    const int t = threadIdx.x;
    const int row0 = blockIdx.x * 64;
    const int ks = blockIdx.y;
    const float4*  P4  = (const float4*)P;    // 1024 float4 per P row
    const ushort4* Bt4 = (const ushort4*)Bt;  // 1024 ushort4 per Bt row

    const int lane = t & 63, w = t >> 6;

    f32x4 acc0 = {0.f, 0.f, 0.f, 0.f};
    f32x4 acc1 = {0.f, 0.f, 0.f, 0.f};

    auto stageA = [&](int c, int buf) {
        const int kc4 = (ks * 512 + c * 128) >> 2;
#pragma unroll
        for (int j = 0; j < 8; ++j) {
            const int i = t + 256 * j;
            const int row = i >> 5, q = i & 31;
            const float4 v = P4[(size_t)(row0 + row) * 1024 + kc4 + q];
            ushort4 u;
            u.x = f2bu(v.x); u.y = f2bu(v.y); u.z = f2bu(v.z); u.w = f2bu(v.w);
            const int wi = row >> 4, m = row & 15;
            const int kk = q >> 3, quad = (q >> 1) & 3, jj = q & 1;
            *(ushort4*)&sA[buf][(((wi * 4 + kk) * 64) + quad * 16 + m) * 8 + jj * 4] = u;
        }
    };
    auto stageB = [&](int c, int buf) {
        const int kc4 = (ks * 512 + c * 128) >> 2;
#pragma unroll
        for (int j = 0; j < 4; ++j) {
            const int i = t + 256 * j;
            const int o = i >> 5, q = i & 31;
            const ushort4 u = Bt4[(size_t)o * 1024 + kc4 + q];
            const int nt = o >> 4, n = o & 15;
            const int kk = q >> 3, quad = (q >> 1) & 3, jj = q & 1;
            *(ushort4*)&sB[buf][(((kk * 2 + nt) * 64) + quad * 16 + n) * 8 + jj * 4] = u;
        }
    };
    auto compute = [&](int buf) {
        const ushort* pa = &sA[buf][(w * 4) * 64 * 8 + lane * 8];
        const ushort* pb = &sB[buf][lane * 8];
#pragma unroll
        for (int kk = 0; kk < 4; ++kk) {
            const bf16x8 a  = *(const bf16x8*)(pa + kk * 512);
            const bf16x8 b0 = *(const bf16x8*)(pb + kk * 1024);
            const bf16x8 b1 = *(const bf16x8*)(pb + kk * 1024 + 512);
            acc0 = __builtin_amdgcn_mfma_f32_16x16x32_bf16(a, b0, acc0, 0, 0, 0);
            acc1 = __builtin_amdgcn_mfma_f32_16x16x32_bf16(a, b1, acc1, 0, 0, 0);
        }
    };

    stageA(0, 0); stageB(0, 0);
    __syncthreads();
    for (int c = 0; c < 4; ++c) {
        if (c < 3) { stageA(c + 1, (c + 1) & 1); stageB(c + 1, (c + 1) & 1); }
        compute(c & 1);
        __syncthreads();
    }

    // C/D layout: col = lane&15, row_in_tile = (lane>>4)*4 + reg
    const int m = lane & 15, quad = lane >> 4;
    float* out = partial + ((size_t)ks * NN + row0 + w * 16 + quad * 4) * 32;
#pragma unroll
    for (int r = 0; r < 4; ++r) {
        out[r * 32 + m]      = acc0[r];
        out[r * 32 + 16 + m] = acc1[r];
    }
}

// ---------------------------------------------------------------------------
// K5: out = z1 + z2 + sum_ks partial[ks]
// ---------------------------------------------------------------------------
__global__ __launch_bounds__(256) void k_combine(
    const float4* __restrict__ z1, const float4* __restrict__ z2,
    const float4* __restrict__ partial, float4* __restrict__ out)
{
    const int i = blockIdx.x * 256 + threadIdx.x;
    const float4 a = z1[i], b = z2[i];
    float rx = a.x + b.x, ry = a.y + b.y, rz = a.z + b.z, rw = a.w + b.w;
#pragma unroll
    for (int p = 0; p < KS; ++p) {
        const float4 c = partial[p * 32768 + i];
        rx += c.x; ry += c.y; rz += c.z; rw += c.w;
    }
    float4 rr; rr.x = rx; rr.y = ry; rr.z = rz; rr.w = rw;
    out[i] = rr;
}

extern "C" void kernel_launch(void* const* d_in, const int* in_sizes, int n_in,
                              void* d_out, int out_size, void* d_ws, size_t ws_size,
                              hipStream_t stream) {
    (void)in_sizes; (void)n_in; (void)out_size; (void)ws_size;
    const float* x    = (const float*)d_in[0];
    const float* Ld   = (const float*)d_in[1];
    const float* Lu   = (const float*)d_in[2];
    const float* P    = (const float*)d_in[3];
    const float* W1   = (const float*)d_in[4];
    const float* W2   = (const float*)d_in[5];
    const float* W0   = (const float*)d_in[6];
    const float* att1 = (const float*)d_in[7];
    const float* att2 = (const float*)d_in[8];

    float* ws = (float*)d_ws;
    float* xwA1 = ws;                 // 131072 each
    float* xwB1 = ws + 131072;
    float* xwA2 = ws + 262144;
    float* xwB2 = ws + 393216;
    float* y1   = ws + 524288;
    float* y2   = ws + 655360;
    float* z1   = ws + 786432;
    float* z2   = ws + 917504;
    float* a1   = ws + 1048576;       // 4096 each
    float* b1   = ws + 1052672;
    float* a2   = ws + 1056768;
    float* b2   = ws + 1060864;
    float* partial = ws + 1064960;    // KS * 131072 floats = 4 MB
    __hip_bfloat16* Bt = (__hip_bfloat16*)(ws + 1064960 + KS * 131072);  // 131072 bf16
    int* csr = (int*)(ws + 1064960 + KS * 131072 + 65536);  // 2*4096*128 ints
    int* cnt = (int*)(ws + 1064960 + KS * 131072 + 65536 + 1048576);  // 8192 ints
    // total ~12.9 MB of workspace

    k_prep<<<512, 256, 0, stream>>>(x, W1, W2, W0, att1, att2,
                                    xwA1, xwB1, xwA2, xwB2, a1, b1, a2, b2, Bt);
    k_scan<<<dim3(NN, 2), 256, 0, stream>>>(Ld, Lu, xwB1, xwB2, csr, cnt, y1, y2);
    k_attn<<<dim3(NN / 4, 2), 256, 0, stream>>>(csr, cnt, a1, b1, a2, b2,
                                                xwA1, xwA2, y1, y2, z1, z2);
    k_pgemm<<<dim3(64, KS), 256, 0, stream>>>(P, (const ushort*)Bt, partial);
    k_combine<<<128, 256, 0, stream>>>((const float4*)z1, (const float4*)z2,
                                       (const float4*)partial, (float4*)d_out);
}

// Round 3
// 235.364 us; speedup vs baseline: 1.4464x; 1.0286x over previous
//
#include <hip/hip_runtime.h>
#include <hip/hip_bf16.h>

#define NN 4096
#define CAP 128   // max nnz per row tracked (binomial mean 41, sd 6.4)
#define KS 8      // k-splits for P-GEMM

typedef __attribute__((ext_vector_type(8))) short bf16x8;
typedef __attribute__((ext_vector_type(4))) float f32x4;

__device__ __forceinline__ float lrelu(float v) { return v >= 0.f ? v : 0.2f * v; }

// fp32 -> bf16 bits, round-to-nearest-even (inputs are finite)
__device__ __forceinline__ ushort f2bu(float f) {
    unsigned u = __float_as_uint(f);
    return (ushort)((u + 0x7FFFu + ((u >> 16) & 1u)) >> 16);
}

// ---------------------------------------------------------------------------
// K1: xwA1=x@W1[0], xwB1=x@W1[1], xwA2=x@W2[0], xwB2=x@W2[1], v0=x@W0,
//     a/b attention vectors, Bt = (x@W0)^T as bf16 for the P-GEMM.
// ---------------------------------------------------------------------------
__global__ __launch_bounds__(256) void k_prep(
    const float* __restrict__ x,
    const float* __restrict__ W1, const float* __restrict__ W2,
    const float* __restrict__ W0,
    const float* __restrict__ att1, const float* __restrict__ att2,
    float* __restrict__ xwA1, float* __restrict__ xwB1,
    float* __restrict__ xwA2, float* __restrict__ xwB2,
    float* __restrict__ a1, float* __restrict__ b1,
    float* __restrict__ a2, float* __restrict__ b2,
    __hip_bfloat16* __restrict__ Bt)
{
    __shared__ float wl[5120];   // W1(2048) W2(2048) W0(1024)
    __shared__ float xs[256];    // 8 rows x 32
    const int t = threadIdx.x;
    for (int i = t; i < 2048; i += 256) { wl[i] = W1[i]; wl[2048 + i] = W2[i]; }
    for (int i = t; i < 1024; i += 256) wl[4096 + i] = W0[i];
    const int rowBase = blockIdx.x * 8;
    xs[t] = x[rowBase * 32 + t];
    __syncthreads();

    const int o = t & 31, r = t >> 5;
    const int row = rowBase + r;
    const float* xr = &xs[r * 32];
    float vA1 = 0.f, vB1 = 0.f, vA2 = 0.f, vB2 = 0.f, v0 = 0.f;
#pragma unroll
    for (int f = 0; f < 32; ++f) {
        const float xv = xr[f];
        vA1 += xv * wl[f * 32 + o];
        vB1 += xv * wl[1024 + f * 32 + o];
        vA2 += xv * wl[2048 + f * 32 + o];
        vB2 += xv * wl[3072 + f * 32 + o];
        v0  += xv * wl[4096 + f * 32 + o];
    }
    xwA1[row * 32 + o] = vA1;
    xwB1[row * 32 + o] = vB1;
    xwA2[row * 32 + o] = vA2;
    xwB2[row * 32 + o] = vB2;
    ((ushort*)Bt)[(size_t)o * NN + row] = f2bu(v0);

    float pa1 = vA1 * att1[o]      + vB1 * att1[32 + o];
    float pb1 = vA1 * att1[64 + o] + vB1 * att1[96 + o];
    float pa2 = vA2 * att2[o]      + vB2 * att2[32 + o];
    float pb2 = vA2 * att2[64 + o] + vB2 * att2[96 + o];
#pragma unroll
    for (int m = 1; m <= 16; m <<= 1) {
        pa1 += __shfl_xor(pa1, m); pb1 += __shfl_xor(pb1, m);
        pa2 += __shfl_xor(pa2, m); pb2 += __shfl_xor(pb2, m);
    }
    if (o == 0) { a1[row] = pa1; b1[row] = pb1; a2[row] = pa2; b2[row] = pb2; }
}

// ---------------------------------------------------------------------------
// K2: per (row, branch): scan dense L row, ballot-compact nonzero columns
// (order scrambled - softmax is order-independent), fused y = L[row,:] @ xwB.
// One LDS atomic per wave per chunk (lane0), zero per-element atomics.
// ---------------------------------------------------------------------------
__global__ __launch_bounds__(256) void k_scan(
    const float* __restrict__ Ld, const float* __restrict__ Lu,
    const float* __restrict__ xwB1, const float* __restrict__ xwB2,
    int* __restrict__ csr, int* __restrict__ cntArr,
    float* __restrict__ y1, float* __restrict__ y2)
{
    const int row = blockIdx.x;
    const int br  = blockIdx.y;
    const float* L   = br ? Lu : Ld;
    const float* xwB = br ? xwB2 : xwB1;
    int*   csrB = csr + (size_t)br * NN * CAP;
    int*   cntB = cntArr + br * NN;
    float* y    = br ? y2 : y1;

    __shared__ int   sidx[CAP];
    __shared__ float sval[CAP];
    __shared__ int   scnt;
    __shared__ float red[256];
    const int t = threadIdx.x;
    const int lane = t & 63;
    if (t == 0) scnt = 0;
    __syncthreads();

    // hoist all 4 float4 loads (64 B/thread in flight)
    const float4* L4 = (const float4*)(L + (size_t)row * NN);
    float4 v[4];
#pragma unroll
    for (int it = 0; it < 4; ++it) v[it] = L4[it * 256 + t];

    const unsigned long long lt = (1ull << lane) - 1ull;
#pragma unroll
    for (int it = 0; it < 4; ++it) {
        const float vx = v[it].x, vy = v[it].y, vz = v[it].z, vw = v[it].w;
        const unsigned long long m0 = __ballot(vx != 0.f);
        const unsigned long long m1 = __ballot(vy != 0.f);
        const unsigned long long m2 = __ballot(vz != 0.f);
        const unsigned long long m3 = __ballot(vw != 0.f);
        const int p0 = __popcll(m0), p1 = __popcll(m1), p2 = __popcll(m2);
        const int tot = p0 + p1 + p2 + __popcll(m3);
        int base = 0;
        if (lane == 0 && tot) base = atomicAdd(&scnt, tot);
        base = __shfl(base, 0);
        const int c0 = (it * 256 + t) * 4;
        int s;
        s = base + __popcll(m0 & lt);
        if (vx != 0.f && s < CAP) { sidx[s] = c0;     sval[s] = vx; }
        s = base + p0 + __popcll(m1 & lt);
        if (vy != 0.f && s < CAP) { sidx[s] = c0 + 1; sval[s] = vy; }
        s = base + p0 + p1 + __popcll(m2 & lt);
        if (vz != 0.f && s < CAP) { sidx[s] = c0 + 2; sval[s] = vz; }
        s = base + p0 + p1 + p2 + __popcll(m3 & lt);
        if (vw != 0.f && s < CAP) { sidx[s] = c0 + 3; sval[s] = vw; }
    }
    __syncthreads();
    const int cnt = min(scnt, CAP);
    for (int s = t; s < cnt; s += 256) csrB[(size_t)row * CAP + s] = sidx[s];
    if (t == 0) cntB[row] = cnt;

    const int o = t & 31, g = t >> 5;
    float acc = 0.f;
    for (int s = g; s < cnt; s += 8) acc += sval[s] * xwB[(size_t)sidx[s] * 32 + o];
    red[t] = acc;
    __syncthreads();
    if (t < 32) {
        float tot2 = 0.f;
#pragma unroll
        for (int g2 = 0; g2 < 8; ++g2) tot2 += red[g2 * 32 + t];
        y[(size_t)row * 32 + t] = tot2;
    }
}

// ---------------------------------------------------------------------------
// K3: per (row, branch) online softmax over CSR entries + weighted gather.
// ---------------------------------------------------------------------------
__global__ __launch_bounds__(256) void k_attn(
    const int* __restrict__ csr, const int* __restrict__ cntArr,
    const float* __restrict__ a1, const float* __restrict__ b1,
    const float* __restrict__ a2, const float* __restrict__ b2,
    const float* __restrict__ xwA1, const float* __restrict__ xwA2,
    const float* __restrict__ y1, const float* __restrict__ y2,
    float* __restrict__ z1, float* __restrict__ z2)
{
    const int br = blockIdx.y;
    const int* csrB = csr + (size_t)br * NN * CAP;
    const int* cntB = cntArr + br * NN;
    const float* aA  = br ? a2 : a1;
    const float* bA  = br ? b2 : b1;
    const float* xwA = br ? xwA2 : xwA1;
    const float* y   = br ? y2 : y1;
    float* z = br ? z2 : z1;

    __shared__ float elds[4 * CAP];
    const int w = threadIdx.x >> 6, lane = threadIdx.x & 63;
    const int row = blockIdx.x * 4 + w;
    const int cnt = cntB[row];
    const float ai = aA[row];
    const int* ci = csrB + (size_t)row * CAP;
    float* ew = elds + w * CAP;

    float lmax = -1e30f;
    for (int s = lane; s < cnt; s += 64) {
        const float e = lrelu(ai + bA[ci[s]]);
        ew[s] = e;
        lmax = fmaxf(lmax, e);
    }
#pragma unroll
    for (int m = 1; m <= 32; m <<= 1) lmax = fmaxf(lmax, __shfl_xor(lmax, m));
    float ssum = 0.f;
    for (int s = lane; s < cnt; s += 64) ssum += __expf(ew[s] - lmax);
#pragma unroll
    for (int m = 1; m <= 32; m <<= 1) ssum += __shfl_xor(ssum, m);

    const int h = lane >> 5, o = lane & 31;
    float acc = 0.f;
    for (int s = h; s < cnt; s += 2) {
        const float wgt = __expf(ew[s] - lmax);
        const int col = ci[s];
        acc += wgt * (xwA[(size_t)col * 32 + o] + y[(size_t)col * 32 + o]);
    }
    acc += __shfl_xor(acc, 32);
    if (lane < 32) z[(size_t)row * 32 + o] = (cnt > 0) ? acc / ssum : 0.f;
}

// ---------------------------------------------------------------------------
// K4 (MFMA): partial[ks] = P[:, krange] @ B[krange, :]
// Block = 64 rows x 32 cols x 512 k; 4 chunks of 128 k, double-buffered LDS.
// ---------------------------------------------------------------------------
__global__ __launch_bounds__(256) void k_pgemm(
    const float* __restrict__ P, const ushort* __restrict__ Bt,
    float* __restrict__ partial)
{
    __shared__ ushort sA[2][16 * 64 * 8];
    __shared__ ushort sB[2][8 * 64 * 8];
    const int t = threadIdx.x;
    const int row0 = blockIdx.x * 64;
    const int ks = blockIdx.y;
    const float4*  P4  = (const float4*)P;
    const ushort4* Bt4 = (const ushort4*)Bt;

    const int lane = t & 63, w = t >> 6;

    f32x4 acc0 = {0.f, 0.f, 0.f, 0.f};
    f32x4 acc1 = {0.f, 0.f, 0.f, 0.f};

    auto stageA = [&](int c, int buf) {
        const int kc4 = (ks * 512 + c * 128) >> 2;
#pragma unroll
        for (int j = 0; j < 8; ++j) {
            const int i = t + 256 * j;
            const int row = i >> 5, q = i & 31;
            const float4 v = P4[(size_t)(row0 + row) * 1024 + kc4 + q];
            ushort4 u;
            u.x = f2bu(v.x); u.y = f2bu(v.y); u.z = f2bu(v.z); u.w = f2bu(v.w);
            const int wi = row >> 4, m = row & 15;
            const int kk = q >> 3, quad = (q >> 1) & 3, jj = q & 1;
            *(ushort4*)&sA[buf][(((wi * 4 + kk) * 64) + quad * 16 + m) * 8 + jj * 4] = u;
        }
    };
    auto stageB = [&](int c, int buf) {
        const int kc4 = (ks * 512 + c * 128) >> 2;
#pragma unroll
        for (int j = 0; j < 4; ++j) {
            const int i = t + 256 * j;
            const int o = i >> 5, q = i & 31;
            const ushort4 u = Bt4[(size_t)o * 1024 + kc4 + q];
            const int nt = o >> 4, n = o & 15;
            const int kk = q >> 3, quad = (q >> 1) & 3, jj = q & 1;
            *(ushort4*)&sB[buf][(((kk * 2 + nt) * 64) + quad * 16 + n) * 8 + jj * 4] = u;
        }
    };
    auto compute = [&](int buf) {
        const ushort* pa = &sA[buf][(w * 4) * 64 * 8 + lane * 8];
        const ushort* pb = &sB[buf][lane * 8];
#pragma unroll
        for (int kk = 0; kk < 4; ++kk) {
            const bf16x8 a  = *(const bf16x8*)(pa + kk * 512);
            const bf16x8 b0 = *(const bf16x8*)(pb + kk * 1024);
            const bf16x8 b1 = *(const bf16x8*)(pb + kk * 1024 + 512);
            acc0 = __builtin_amdgcn_mfma_f32_16x16x32_bf16(a, b0, acc0, 0, 0, 0);
            acc1 = __builtin_amdgcn_mfma_f32_16x16x32_bf16(a, b1, acc1, 0, 0, 0);
        }
    };

    stageA(0, 0); stageB(0, 0);
    __syncthreads();
    for (int c = 0; c < 4; ++c) {
        if (c < 3) { stageA(c + 1, (c + 1) & 1); stageB(c + 1, (c + 1) & 1); }
        compute(c & 1);
        __syncthreads();
    }

    const int m = lane & 15, quad = lane >> 4;
    float* out = partial + ((size_t)ks * NN + row0 + w * 16 + quad * 4) * 32;
#pragma unroll
    for (int r = 0; r < 4; ++r) {
        out[r * 32 + m]      = acc0[r];
        out[r * 32 + 16 + m] = acc1[r];
    }
}

// ---------------------------------------------------------------------------
// K5: out = z1 + z2 + sum_ks partial[ks]
// ---------------------------------------------------------------------------
__global__ __launch_bounds__(256) void k_combine(
    const float4* __restrict__ z1, const float4* __restrict__ z2,
    const float4* __restrict__ partial, float4* __restrict__ out)
{
    const int i = blockIdx.x * 256 + threadIdx.x;
    const float4 a = z1[i], b = z2[i];
    float rx = a.x + b.x, ry = a.y + b.y, rz = a.z + b.z, rw = a.w + b.w;
#pragma unroll
    for (int p = 0; p < KS; ++p) {
        const float4 c = partial[p * 32768 + i];
        rx += c.x; ry += c.y; rz += c.z; rw += c.w;
    }
    float4 rr; rr.x = rx; rr.y = ry; rr.z = rz; rr.w = rw;
    out[i] = rr;
}

extern "C" void kernel_launch(void* const* d_in, const int* in_sizes, int n_in,
                              void* d_out, int out_size, void* d_ws, size_t ws_size,
                              hipStream_t stream) {
    (void)in_sizes; (void)n_in; (void)out_size; (void)ws_size;
    const float* x    = (const float*)d_in[0];
    const float* Ld   = (const float*)d_in[1];
    const float* Lu   = (const float*)d_in[2];
    const float* P    = (const float*)d_in[3];
    const float* W1   = (const float*)d_in[4];
    const float* W2   = (const float*)d_in[5];
    const float* W0   = (const float*)d_in[6];
    const float* att1 = (const float*)d_in[7];
    const float* att2 = (const float*)d_in[8];

    float* ws = (float*)d_ws;
    float* xwA1 = ws;                 // 131072 each
    float* xwB1 = ws + 131072;
    float* xwA2 = ws + 262144;
    float* xwB2 = ws + 393216;
    float* y1   = ws + 524288;
    float* y2   = ws + 655360;
    float* z1   = ws + 786432;
    float* z2   = ws + 917504;
    float* a1   = ws + 1048576;       // 4096 each
    float* b1   = ws + 1052672;
    float* a2   = ws + 1056768;
    float* b2   = ws + 1060864;
    float* partial = ws + 1064960;    // KS * 131072 floats = 4 MB
    __hip_bfloat16* Bt = (__hip_bfloat16*)(ws + 1064960 + KS * 131072);  // 131072 bf16
    int* csr = (int*)(ws + 1064960 + KS * 131072 + 65536);  // 2*4096*128 ints
    int* cnt = (int*)(ws + 1064960 + KS * 131072 + 65536 + 1048576);  // 8192 ints

    k_prep<<<512, 256, 0, stream>>>(x, W1, W2, W0, att1, att2,
                                    xwA1, xwB1, xwA2, xwB2, a1, b1, a2, b2, Bt);
    k_scan<<<dim3(NN, 2), 256, 0, stream>>>(Ld, Lu, xwB1, xwB2, csr, cnt, y1, y2);
    k_attn<<<dim3(NN / 4, 2), 256, 0, stream>>>(csr, cnt, a1, b1, a2, b2,
                                                xwA1, xwA2, y1, y2, z1, z2);
    k_pgemm<<<dim3(64, KS), 256, 0, stream>>>(P, (const ushort*)Bt, partial);
    k_combine<<<128, 256, 0, stream>>>((const float4*)z1, (const float4*)z2,
                                       (const float4*)partial, (float4*)d_out);
}

// Round 4
// 225.788 us; speedup vs baseline: 1.5077x; 1.0424x over previous
//
#include <hip/hip_runtime.h>
#include <hip/hip_bf16.h>

#define NN 4096
#define CAP 128   // max nnz per row tracked (binomial mean 41, sd 6.4)
#define KS 8      // k-splits for P-GEMM

typedef __attribute__((ext_vector_type(8))) short bf16x8;
typedef __attribute__((ext_vector_type(4))) float f32x4;

__device__ __forceinline__ float lrelu(float v) { return v >= 0.f ? v : 0.2f * v; }

// fp32 -> bf16 bits, round-to-nearest-even (inputs are finite)
__device__ __forceinline__ ushort f2bu(float f) {
    unsigned u = __float_as_uint(f);
    return (ushort)((u + 0x7FFFu + ((u >> 16) & 1u)) >> 16);
}

// ---------------------------------------------------------------------------
// K1: xwA1=x@W1[0], xwB1=x@W1[1], xwA2=x@W2[0], xwB2=x@W2[1], v0=x@W0,
//     a/b attention vectors, Bt = (x@W0)^T as bf16 for the P-GEMM.
// ---------------------------------------------------------------------------
__global__ __launch_bounds__(256) void k_prep(
    const float* __restrict__ x,
    const float* __restrict__ W1, const float* __restrict__ W2,
    const float* __restrict__ W0,
    const float* __restrict__ att1, const float* __restrict__ att2,
    float* __restrict__ xwA1, float* __restrict__ xwB1,
    float* __restrict__ xwA2, float* __restrict__ xwB2,
    float* __restrict__ a1, float* __restrict__ b1,
    float* __restrict__ a2, float* __restrict__ b2,
    __hip_bfloat16* __restrict__ Bt)
{
    __shared__ float wl[5120];   // W1(2048) W2(2048) W0(1024)
    __shared__ float xs[256];    // 8 rows x 32
    const int t = threadIdx.x;
    for (int i = t; i < 2048; i += 256) { wl[i] = W1[i]; wl[2048 + i] = W2[i]; }
    for (int i = t; i < 1024; i += 256) wl[4096 + i] = W0[i];
    const int rowBase = blockIdx.x * 8;
    xs[t] = x[rowBase * 32 + t];
    __syncthreads();

    const int o = t & 31, r = t >> 5;
    const int row = rowBase + r;
    const float* xr = &xs[r * 32];
    float vA1 = 0.f, vB1 = 0.f, vA2 = 0.f, vB2 = 0.f, v0 = 0.f;
#pragma unroll
    for (int f = 0; f < 32; ++f) {
        const float xv = xr[f];
        vA1 += xv * wl[f * 32 + o];
        vB1 += xv * wl[1024 + f * 32 + o];
        vA2 += xv * wl[2048 + f * 32 + o];
        vB2 += xv * wl[3072 + f * 32 + o];
        v0  += xv * wl[4096 + f * 32 + o];
    }
    xwA1[row * 32 + o] = vA1;
    xwB1[row * 32 + o] = vB1;
    xwA2[row * 32 + o] = vA2;
    xwB2[row * 32 + o] = vB2;
    ((ushort*)Bt)[(size_t)o * NN + row] = f2bu(v0);

    float pa1 = vA1 * att1[o]      + vB1 * att1[32 + o];
    float pb1 = vA1 * att1[64 + o] + vB1 * att1[96 + o];
    float pa2 = vA2 * att2[o]      + vB2 * att2[32 + o];
    float pb2 = vA2 * att2[64 + o] + vB2 * att2[96 + o];
#pragma unroll
    for (int m = 1; m <= 16; m <<= 1) {
        pa1 += __shfl_xor(pa1, m); pb1 += __shfl_xor(pb1, m);
        pa2 += __shfl_xor(pa2, m); pb2 += __shfl_xor(pb2, m);
    }
    if (o == 0) { a1[row] = pa1; b1[row] = pb1; a2[row] = pa2; b2[row] = pb2; }
}

// ---------------------------------------------------------------------------
// K2: per (row, branch): scan dense L row, two-phase ballot compaction
// (per-wave counts -> prefix, zero atomics), pad list to mult-of-16 with
// (idx=0,val=0) sentinels, then batched+pipelined gather for
// u[row] = xwA[row] + L[row,:] @ xwB.
// ---------------------------------------------------------------------------
__global__ __launch_bounds__(256) void k_scan(
    const float* __restrict__ Ld, const float* __restrict__ Lu,
    const float* __restrict__ xwB1, const float* __restrict__ xwB2,
    const float* __restrict__ xwA1, const float* __restrict__ xwA2,
    int* __restrict__ csr, int* __restrict__ cntArr,
    float* __restrict__ u1, float* __restrict__ u2)
{
    const int row = blockIdx.x;
    const int br  = blockIdx.y;
    const float* L   = br ? Lu : Ld;
    const float* xwB = br ? xwB2 : xwB1;
    const float* xwA = br ? xwA2 : xwA1;
    int*   csrB = csr + (size_t)br * NN * CAP;
    int*   cntB = cntArr + br * NN;
    float* u    = br ? u2 : u1;

    __shared__ int   sidx[CAP];
    __shared__ float sval[CAP];
    __shared__ int   wcnt[16];
    __shared__ float red[256];
    const int t = threadIdx.x;
    const int lane = t & 63, w = t >> 6;

    // hoist all 4 float4 loads (64 B/thread in flight)
    const float4* L4 = (const float4*)(L + (size_t)row * NN);
    float4 v[4];
#pragma unroll
    for (int it = 0; it < 4; ++it) v[it] = L4[it * 256 + t];

    const unsigned long long lt = (1ull << lane) - 1ull;

    // phase 1: per-(wave,iter) nonzero counts
    int tots[4];
#pragma unroll
    for (int it = 0; it < 4; ++it) {
        const unsigned long long m0 = __ballot(v[it].x != 0.f);
        const unsigned long long m1 = __ballot(v[it].y != 0.f);
        const unsigned long long m2 = __ballot(v[it].z != 0.f);
        const unsigned long long m3 = __ballot(v[it].w != 0.f);
        tots[it] = __popcll(m0) + __popcll(m1) + __popcll(m2) + __popcll(m3);
    }
    if (lane == 0) {
        int4 tv; tv.x = tots[0]; tv.y = tots[1]; tv.z = tots[2]; tv.w = tots[3];
        *(int4*)&wcnt[w * 4] = tv;
    }
    __syncthreads();

    // phase 2: prefix over 16 counts, compact into LDS
    const int4 ca = *(const int4*)&wcnt[0];
    const int4 cb = *(const int4*)&wcnt[4];
    const int4 cc = *(const int4*)&wcnt[8];
    const int4 cd = *(const int4*)&wcnt[12];
    const int cs[16] = {ca.x, ca.y, ca.z, ca.w, cb.x, cb.y, cb.z, cb.w,
                        cc.x, cc.y, cc.z, cc.w, cd.x, cd.y, cd.z, cd.w};
    int total = 0;
#pragma unroll
    for (int k2 = 0; k2 < 16; ++k2) total += cs[k2];
    int base = 0;
#pragma unroll
    for (int k2 = 0; k2 < 16; ++k2) base += (k2 < (w << 2)) ? cs[k2] : 0;

    const int cnt  = min(total, CAP);
    const int cp16 = min((cnt + 15) & ~15, CAP);

#pragma unroll
    for (int it = 0; it < 4; ++it) {
        const float vx = v[it].x, vy = v[it].y, vz = v[it].z, vw = v[it].w;
        const unsigned long long m0 = __ballot(vx != 0.f);
        const unsigned long long m1 = __ballot(vy != 0.f);
        const unsigned long long m2 = __ballot(vz != 0.f);
        const unsigned long long m3 = __ballot(vw != 0.f);
        const int p0 = __popcll(m0), p1 = __popcll(m1), p2 = __popcll(m2);
        const int c0 = (it * 256 + t) * 4;
        int s;
        s = base + __popcll(m0 & lt);
        if (vx != 0.f && s < CAP) { sidx[s] = c0;     sval[s] = vx; }
        s = base + p0 + __popcll(m1 & lt);
        if (vy != 0.f && s < CAP) { sidx[s] = c0 + 1; sval[s] = vy; }
        s = base + p0 + p1 + __popcll(m2 & lt);
        if (vz != 0.f && s < CAP) { sidx[s] = c0 + 2; sval[s] = vz; }
        s = base + p0 + p1 + p2 + __popcll(m3 & lt);
        if (vw != 0.f && s < CAP) { sidx[s] = c0 + 3; sval[s] = vw; }
        base += p0 + p1 + p2 + __popcll(m3);
    }
    // sentinel padding: safe idx 0, weight 0
    if (t >= cnt && t < cp16) { sidx[t] = 0; sval[t] = 0.f; }
    __syncthreads();

    if (t < cp16) csrB[(size_t)row * CAP + t] = sidx[t];
    if (t == 0)   cntB[row] = cnt;

    // batched (2/batch) + depth-2 pipelined gather: 4 loads in flight
    const int o = t & 31, g = t >> 5;
    float acc = 0.f;
    const int nPair = cp16 >> 4;     // 16 slots per batch: 2 per group
    if (nPair > 0) {
        int   iA0 = sidx[g],      iA1 = sidx[g + 8];
        float vA0 = sval[g],      vA1 = sval[g + 8];
        float xA0 = xwB[(size_t)iA0 * 32 + o];
        float xA1 = xwB[(size_t)iA1 * 32 + o];
        for (int j = 1; j < nPair; ++j) {
            const int sB = g + 16 * j;
            const int   iB0 = sidx[sB],  iB1 = sidx[sB + 8];
            const float vB0 = sval[sB],  vB1 = sval[sB + 8];
            const float xB0 = xwB[(size_t)iB0 * 32 + o];
            const float xB1 = xwB[(size_t)iB1 * 32 + o];
            acc += vA0 * xA0 + vA1 * xA1;
            vA0 = vB0; xA0 = xB0; vA1 = vB1; xA1 = xB1;
        }
        acc += vA0 * xA0 + vA1 * xA1;
    }
    red[t] = acc;
    __syncthreads();
    if (t < 32) {
        float tot2 = 0.f;
#pragma unroll
        for (int g2 = 0; g2 < 8; ++g2) tot2 += red[g2 * 32 + t];
        u[(size_t)row * 32 + t] = tot2 + xwA[(size_t)row * 32 + t];
    }
}

// ---------------------------------------------------------------------------
// K3: per (row, branch) softmax over CSR entries + weighted gather of
// U = xwA + y (pre-fused in k_scan). Wave per row; exp computed once into
// LDS; gather batched x4 + pipelined depth 2 (8 loads in flight).
// ---------------------------------------------------------------------------
__global__ __launch_bounds__(256) void k_attn(
    const int* __restrict__ csr, const int* __restrict__ cntArr,
    const float* __restrict__ a1, const float* __restrict__ b1,
    const float* __restrict__ a2, const float* __restrict__ b2,
    const float* __restrict__ u1, const float* __restrict__ u2,
    float* __restrict__ z1, float* __restrict__ z2)
{
    const int br = blockIdx.y;
    const int* csrB = csr + (size_t)br * NN * CAP;
    const int* cntB = cntArr + br * NN;
    const float* aA = br ? a2 : a1;
    const float* bA = br ? b2 : b1;
    const float* U  = br ? u2 : u1;
    float* z = br ? z2 : z1;

    __shared__ float sw[4 * CAP];
    __shared__ int   sci[4 * CAP];
    const int w = threadIdx.x >> 6, lane = threadIdx.x & 63;
    const int row = blockIdx.x * 4 + w;
    const int cnt = cntB[row];
    const int cp16 = min((cnt + 15) & ~15, CAP);
    const float ai = aA[row];
    const int* ci = csrB + (size_t)row * CAP;
    float* swg = sw + w * CAP;
    int*   scg = sci + w * CAP;

    int id0 = 0, id1 = 0;
    if (lane < cp16)      id0 = ci[lane];
    if (lane + 64 < cp16) id1 = ci[lane + 64];
    float e0 = (lane < cnt)      ? lrelu(ai + bA[id0]) : -1e30f;
    float e1 = (lane + 64 < cnt) ? lrelu(ai + bA[id1]) : -1e30f;
    float lmax = fmaxf(e0, e1);
#pragma unroll
    for (int m = 1; m <= 32; m <<= 1) lmax = fmaxf(lmax, __shfl_xor(lmax, m));
    const float w0 = __expf(e0 - lmax), w1 = __expf(e1 - lmax);
    float ssum = w0 + w1;
#pragma unroll
    for (int m = 1; m <= 32; m <<= 1) ssum += __shfl_xor(ssum, m);
    swg[lane] = w0; swg[lane + 64] = w1;
    scg[lane] = id0; scg[lane + 64] = id1;
    // wave-private LDS segment: lgkmcnt wait (compiler-inserted) suffices

    const int o = lane & 31, h = lane >> 5;
    float acc = 0.f;
    const int nb = cp16 >> 3;    // 8 slots/batch, 4 per half
    if (cnt > 0) {
        float wgA[4], uvA[4];
#pragma unroll
        for (int q = 0; q < 4; ++q) {
            const int s = h + 2 * q;
            wgA[q] = swg[s];
            uvA[q] = U[(size_t)scg[s] * 32 + o];
        }
        for (int j = 1; j < nb; ++j) {
            float wgB[4], uvB[4];
#pragma unroll
            for (int q = 0; q < 4; ++q) {
                const int s = h + 8 * j + 2 * q;
                wgB[q] = swg[s];
                uvB[q] = U[(size_t)scg[s] * 32 + o];
            }
#pragma unroll
            for (int q = 0; q < 4; ++q) acc += wgA[q] * uvA[q];
#pragma unroll
            for (int q = 0; q < 4; ++q) { wgA[q] = wgB[q]; uvA[q] = uvB[q]; }
        }
#pragma unroll
        for (int q = 0; q < 4; ++q) acc += wgA[q] * uvA[q];
    }
    acc += __shfl_xor(acc, 32);
    if (lane < 32) z[(size_t)row * 32 + o] = (cnt > 0) ? acc / ssum : 0.f;
}

// ---------------------------------------------------------------------------
// K4 (MFMA): partial[ks] = P[:, krange] @ B[krange, :]
// Block = 64 rows x 32 cols x 512 k; 4 chunks of 128 k, double-buffered LDS.
// ---------------------------------------------------------------------------
__global__ __launch_bounds__(256) void k_pgemm(
    const float* __restrict__ P, const ushort* __restrict__ Bt,
    float* __restrict__ partial)
{
    __shared__ ushort sA[2][16 * 64 * 8];
    __shared__ ushort sB[2][8 * 64 * 8];
    const int t = threadIdx.x;
    const int row0 = blockIdx.x * 64;
    const int ks = blockIdx.y;
    const float4*  P4  = (const float4*)P;
    const ushort4* Bt4 = (const ushort4*)Bt;

    const int lane = t & 63, w = t >> 6;

    f32x4 acc0 = {0.f, 0.f, 0.f, 0.f};
    f32x4 acc1 = {0.f, 0.f, 0.f, 0.f};

    auto stageA = [&](int c, int buf) {
        const int kc4 = (ks * 512 + c * 128) >> 2;
#pragma unroll
        for (int j = 0; j < 8; ++j) {
            const int i = t + 256 * j;
            const int row = i >> 5, q = i & 31;
            const float4 v = P4[(size_t)(row0 + row) * 1024 + kc4 + q];
            ushort4 u;
            u.x = f2bu(v.x); u.y = f2bu(v.y); u.z = f2bu(v.z); u.w = f2bu(v.w);
            const int wi = row >> 4, m = row & 15;
            const int kk = q >> 3, quad = (q >> 1) & 3, jj = q & 1;
            *(ushort4*)&sA[buf][(((wi * 4 + kk) * 64) + quad * 16 + m) * 8 + jj * 4] = u;
        }
    };
    auto stageB = [&](int c, int buf) {
        const int kc4 = (ks * 512 + c * 128) >> 2;
#pragma unroll
        for (int j = 0; j < 4; ++j) {
            const int i = t + 256 * j;
            const int o = i >> 5, q = i & 31;
            const ushort4 u = Bt4[(size_t)o * 1024 + kc4 + q];
            const int nt = o >> 4, n = o & 15;
            const int kk = q >> 3, quad = (q >> 1) & 3, jj = q & 1;
            *(ushort4*)&sB[buf][(((kk * 2 + nt) * 64) + quad * 16 + n) * 8 + jj * 4] = u;
        }
    };
    auto compute = [&](int buf) {
        const ushort* pa = &sA[buf][(w * 4) * 64 * 8 + lane * 8];
        const ushort* pb = &sB[buf][lane * 8];
#pragma unroll
        for (int kk = 0; kk < 4; ++kk) {
            const bf16x8 a  = *(const bf16x8*)(pa + kk * 512);
            const bf16x8 b0 = *(const bf16x8*)(pb + kk * 1024);
            const bf16x8 b1 = *(const bf16x8*)(pb + kk * 1024 + 512);
            acc0 = __builtin_amdgcn_mfma_f32_16x16x32_bf16(a, b0, acc0, 0, 0, 0);
            acc1 = __builtin_amdgcn_mfma_f32_16x16x32_bf16(a, b1, acc1, 0, 0, 0);
        }
    };

    stageA(0, 0); stageB(0, 0);
    __syncthreads();
    for (int c = 0; c < 4; ++c) {
        if (c < 3) { stageA(c + 1, (c + 1) & 1); stageB(c + 1, (c + 1) & 1); }
        compute(c & 1);
        __syncthreads();
    }

    const int m = lane & 15, quad = lane >> 4;
    float* out = partial + ((size_t)ks * NN + row0 + w * 16 + quad * 4) * 32;
#pragma unroll
    for (int r = 0; r < 4; ++r) {
        out[r * 32 + m]      = acc0[r];
        out[r * 32 + 16 + m] = acc1[r];
    }
}

// ---------------------------------------------------------------------------
// K5: out = z1 + z2 + sum_ks partial[ks]
// ---------------------------------------------------------------------------
__global__ __launch_bounds__(256) void k_combine(
    const float4* __restrict__ z1, const float4* __restrict__ z2,
    const float4* __restrict__ partial, float4* __restrict__ out)
{
    const int i = blockIdx.x * 256 + threadIdx.x;
    const float4 a = z1[i], b = z2[i];
    float rx = a.x + b.x, ry = a.y + b.y, rz = a.z + b.z, rw = a.w + b.w;
#pragma unroll
    for (int p = 0; p < KS; ++p) {
        const float4 c = partial[p * 32768 + i];
        rx += c.x; ry += c.y; rz += c.z; rw += c.w;
    }
    float4 rr; rr.x = rx; rr.y = ry; rr.z = rz; rr.w = rw;
    out[i] = rr;
}

extern "C" void kernel_launch(void* const* d_in, const int* in_sizes, int n_in,
                              void* d_out, int out_size, void* d_ws, size_t ws_size,
                              hipStream_t stream) {
    (void)in_sizes; (void)n_in; (void)out_size; (void)ws_size;
    const float* x    = (const float*)d_in[0];
    const float* Ld   = (const float*)d_in[1];
    const float* Lu   = (const float*)d_in[2];
    const float* P    = (const float*)d_in[3];
    const float* W1   = (const float*)d_in[4];
    const float* W2   = (const float*)d_in[5];
    const float* W0   = (const float*)d_in[6];
    const float* att1 = (const float*)d_in[7];
    const float* att2 = (const float*)d_in[8];

    float* ws = (float*)d_ws;
    float* xwA1 = ws;                 // 131072 each
    float* xwB1 = ws + 131072;
    float* xwA2 = ws + 262144;
    float* xwB2 = ws + 393216;
    float* u1   = ws + 524288;        // xwA + L@xwB (fused)
    float* u2   = ws + 655360;
    float* z1   = ws + 786432;
    float* z2   = ws + 917504;
    float* a1   = ws + 1048576;       // 4096 each
    float* b1   = ws + 1052672;
    float* a2   = ws + 1056768;
    float* b2   = ws + 1060864;
    float* partial = ws + 1064960;    // KS * 131072 floats = 4 MB
    __hip_bfloat16* Bt = (__hip_bfloat16*)(ws + 1064960 + KS * 131072);  // 131072 bf16
    int* csr = (int*)(ws + 1064960 + KS * 131072 + 65536);  // 2*4096*128 ints
    int* cnt = (int*)(ws + 1064960 + KS * 131072 + 65536 + 1048576);  // 8192 ints

    k_prep<<<512, 256, 0, stream>>>(x, W1, W2, W0, att1, att2,
                                    xwA1, xwB1, xwA2, xwB2, a1, b1, a2, b2, Bt);
    k_scan<<<dim3(NN, 2), 256, 0, stream>>>(Ld, Lu, xwB1, xwB2, xwA1, xwA2,
                                            csr, cnt, u1, u2);
    k_attn<<<dim3(NN / 4, 2), 256, 0, stream>>>(csr, cnt, a1, b1, a2, b2,
                                                u1, u2, z1, z2);
    k_pgemm<<<dim3(64, KS), 256, 0, stream>>>(P, (const ushort*)Bt, partial);
    k_combine<<<128, 256, 0, stream>>>((const float4*)z1, (const float4*)z2,
                                       (const float4*)partial, (float4*)d_out);
}